// Round 3
// baseline (455.758 us; speedup 1.0000x reference)
//
#include <hip/hip_runtime.h>
#include <cstddef>

// Problem constants
#define NB 16
#define NVOX 128
#define NPT 1920
#define NPAIRS 32768   // 16 b * 16 tz * 16 ty * 8 x-pairs

static __device__ __forceinline__ float2 f2(float a, float b) {
    float2 r; r.x = a; r.y = b; return r;
}

// ---------------------------------------------------------------------------
// Stage 1: Conv1d(256,240,1) on the (256,8) view, all 16 batches.
// One block per output channel o (240 blocks). w1 row staged coalesced in LDS;
// thread = (half, b, l) computes a split-K partial; pair-combined at the end.
// x1g layout: [b][o*8+l]  (matches (240,8) == (64,30) flat view downstream).
// ---------------------------------------------------------------------------
__global__ __launch_bounds__(256)
void mlp_stage1(const float* __restrict__ q, const float* __restrict__ w1,
                const float* __restrict__ b1, float* __restrict__ x1g)
{
    __shared__ float wrow[256];
    __shared__ float psum[256];
    const int o = blockIdx.x;
    const int t = threadIdx.x;

    wrow[t] = w1[o * 256 + t];
    __syncthreads();

    const int half = t >> 7;       // K-split: i in [half*128, half*128+128)
    const int bl = t & 127;
    const int b = bl >> 3, l = bl & 7;
    const float* qb = q + b * 2048 + l + half * 1024;  // q[b][i*8+l]
    float s = 0.f;
    #pragma unroll 8
    for (int i = 0; i < 128; ++i)
        s = fmaf(wrow[half * 128 + i], qb[i * 8], s);
    psum[t] = s;
    __syncthreads();

    if (t < 128) {
        int bb = t >> 3, ll = t & 7;
        x1g[bb * 1920 + o * 8 + ll] = b1[o] + psum[t] + psum[t + 128];
    }
}

// ---------------------------------------------------------------------------
// Tail v3: wave-per-channel. The grouped convs never mix channels, so final
// channel c3 = wave w depends only on IN1 channels 4w..4w+3. Each wave
// carries IN1 -> conv2 -> IN2 -> conv3 -> IN3 -> IN4-stats entirely in
// registers with __shfl_xor butterfly reductions. ONE block barrier total,
// then the cross-channel per-point einsum.
// Lane layout: c1_local = lane>>4 (4 IN1 channels), p16 = lane&15; each lane
// owns row elements {p16, p16+16 (if <30)}.
// ---------------------------------------------------------------------------
__global__ __launch_bounds__(1024)
void mlp_tail(const float* __restrict__ x1g, const float* __restrict__ qval,
              const float* __restrict__ w2, const float* __restrict__ b2,
              const float* __restrict__ w3, const float* __restrict__ b3,
              const float* __restrict__ w4, const float* __restrict__ b4,
              const float* __restrict__ w5, const float* __restrict__ b5,
              float4* __restrict__ pts, unsigned char* __restrict__ flags)
{
    __shared__ float h3[16 * 480];     // relu'd IN3 output (c3, 480)
    __shared__ float m4s[16], r4s[16];

    const int b = blockIdx.x;
    const int t = threadIdx.x;
    const int w = t >> 6;        // wave id == final channel c3
    const int l = t & 63;

    const int c1l = l >> 4;      // 0..3
    const int p16 = l & 15;
    const int c1  = 4 * w + c1l;
    const bool hasb = (p16 < 14);   // second element p16+16 < 30

    // --- load this wave's x1 rows (flat (64,30) view of stage1 output) ---
    const float* xrow = x1g + b * 1920 + c1 * 30;
    float a0 = xrow[p16];
    float a1 = hasb ? xrow[p16 + 16] : 0.f;

    // --- IN1 over 30 elems: butterfly within the 16-lane channel group ---
    float s = a0 + a1, s2 = a0 * a0 + a1 * a1;
    #pragma unroll
    for (int m = 1; m <= 8; m <<= 1) {
        s  += __shfl_xor(s,  m);
        s2 += __shfl_xor(s2, m);
    }
    float mean = s * (1.f / 30.f);
    float var  = s2 * (1.f / 30.f) - mean * mean;
    float rstd = rsqrtf(var + 1e-5f);
    a0 = fmaxf((a0 - mean) * rstd, 0.f);
    a1 = fmaxf((a1 - mean) * rstd, 0.f);    // garbage if !hasb; masked below

    // --- stage2: grouped conv 64->128 (per-lane elementwise) ---
    const float w20 = w2[c1 * 2 + 0], w21 = w2[c1 * 2 + 1];
    const float b20 = b2[c1 * 2 + 0], b21 = b2[c1 * 2 + 1];
    float y00 = fmaf(a0, w20, b20), y01 = fmaf(a0, w21, b21);
    float y10 = fmaf(a1, w20, b20), y11 = fmaf(a1, w21, b21);

    // --- IN2 over 120 elems: butterfly within the 32-lane half (c2 group) ---
    float u = y00 + y01 + (hasb ? (y10 + y11) : 0.f);
    float u2 = y00 * y00 + y01 * y01 + (hasb ? (y10 * y10 + y11 * y11) : 0.f);
    #pragma unroll
    for (int m = 1; m <= 16; m <<= 1) {
        u  += __shfl_xor(u,  m);
        u2 += __shfl_xor(u2, m);
    }
    mean = u * (1.f / 120.f);
    var  = u2 * (1.f / 120.f) - mean * mean;
    rstd = rsqrtf(var + 1e-5f);
    y00 = fmaxf((y00 - mean) * rstd, 0.f);
    y01 = fmaxf((y01 - mean) * rstd, 0.f);
    y10 = fmaxf((y10 - mean) * rstd, 0.f);
    y11 = fmaxf((y11 - mean) * rstd, 0.f);

    // --- stage3: grouped conv 32->64 ---
    const int c2 = c1 >> 1;
    const float w30 = w3[c2 * 2 + 0], w31 = w3[c2 * 2 + 1];
    const float b30 = b3[c2 * 2 + 0], b31 = b3[c2 * 2 + 1];
    float z000 = fmaf(y00, w30, b30), z001 = fmaf(y00, w31, b31);
    float z010 = fmaf(y01, w30, b30), z011 = fmaf(y01, w31, b31);
    float z100 = fmaf(y10, w30, b30), z101 = fmaf(y10, w31, b31);
    float z110 = fmaf(y11, w30, b30), z111 = fmaf(y11, w31, b31);

    // --- IN3 over 480 elems: full-wave butterfly ---
    float v1 = z000 + z001 + z010 + z011
             + (hasb ? (z100 + z101 + z110 + z111) : 0.f);
    float v2 = z000 * z000 + z001 * z001 + z010 * z010 + z011 * z011
             + (hasb ? (z100 * z100 + z101 * z101 + z110 * z110 + z111 * z111) : 0.f);
    #pragma unroll
    for (int m = 1; m <= 32; m <<= 1) {
        v1 += __shfl_xor(v1, m);
        v2 += __shfl_xor(v2, m);
    }
    mean = v1 * (1.f / 480.f);
    var  = v2 * (1.f / 480.f) - mean * mean;
    rstd = rsqrtf(var + 1e-5f);

    // --- normalize+relu, store to h3, accumulate relu'd sums for IN4 ---
    // q = ((c2&1)*2 + j2)*120 + ((c1&1)*2 + j1)*30 + p1
    const int qb0 = (c1l >> 1) * 240;        // (c2&1)*2*120
    const int pb0 = (c1l & 1) * 60;          // (c1&1)*2*30
    float* hw = h3 + w * 480;
    float s4 = 0.f, q4 = 0.f;
    {
        float v;
        v = fmaxf((z000 - mean) * rstd, 0.f); hw[qb0 +       pb0 +      p16] = v; s4 += v; q4 += v * v;
        v = fmaxf((z001 - mean) * rstd, 0.f); hw[qb0 + 120 + pb0 +      p16] = v; s4 += v; q4 += v * v;
        v = fmaxf((z010 - mean) * rstd, 0.f); hw[qb0 +       pb0 + 30 + p16] = v; s4 += v; q4 += v * v;
        v = fmaxf((z011 - mean) * rstd, 0.f); hw[qb0 + 120 + pb0 + 30 + p16] = v; s4 += v; q4 += v * v;
        if (hasb) {
            v = fmaxf((z100 - mean) * rstd, 0.f); hw[qb0 +       pb0 +      p16 + 16] = v; s4 += v; q4 += v * v;
            v = fmaxf((z101 - mean) * rstd, 0.f); hw[qb0 + 120 + pb0 +      p16 + 16] = v; s4 += v; q4 += v * v;
            v = fmaxf((z110 - mean) * rstd, 0.f); hw[qb0 +       pb0 + 30 + p16 + 16] = v; s4 += v; q4 += v * v;
            v = fmaxf((z111 - mean) * rstd, 0.f); hw[qb0 + 120 + pb0 + 30 + p16 + 16] = v; s4 += v; q4 += v * v;
        }
    }
    #pragma unroll
    for (int m = 1; m <= 32; m <<= 1) {
        s4 += __shfl_xor(s4, m);
        q4 += __shfl_xor(q4, m);
    }
    if (l == 0) {
        // stage4 IN stats analytically: x4[c, j*480+p] = h3[c,p]*w4[c*4+j]+b4[c*4+j]
        float sum4 = 0.f, sq4 = 0.f;
        #pragma unroll
        for (int j = 0; j < 4; ++j) {
            float ww = w4[w * 4 + j], bb = b4[w * 4 + j];
            sum4 += ww * s4 + 480.f * bb;
            sq4  += ww * ww * q4 + 2.f * ww * bb * s4 + 480.f * bb * bb;
        }
        float m4 = sum4 * (1.f / 1920.f);
        float var4 = sq4 * (1.f / 1920.f) - m4 * m4;
        m4s[w] = m4; r4s[w] = rsqrtf(var4 + 1e-5f);
    }
    __syncthreads();    // the only block barrier

    // --- per-point: stage4 apply + stage5 einsum + tanh + emit + mark pairs ---
    for (int p = t; p < NPT; p += 1024) {
        int j = p / 480;
        int pp = p - j * 480;
        float a0e = b5[0], a1e = b5[1], a2e = b5[2];
        #pragma unroll
        for (int c = 0; c < 16; ++c) {
            float xv = h3[c * 480 + pp];
            float x4 = fmaf(xv, w4[c * 4 + j], b4[c * 4 + j]);
            float h  = fmaxf((x4 - m4s[c]) * r4s[c], 0.f);
            a0e = fmaf(w5[c],      h, a0e);
            a1e = fmaf(w5[16 + c], h, a1e);
            a2e = fmaf(w5[32 + c], h, a2e);
        }
        float px = tanhf(a0e) * 64.f + 63.5f;
        float py = tanhf(a1e) * 64.f + 63.5f;
        float pz = tanhf(a2e) * 64.f + 63.5f;
        float val = 1.f / (1.f + expf(-qval[p]));

        float4 pv; pv.x = px; pv.y = py; pv.z = pz; pv.w = val;
        pts[b * NPT + p] = pv;

        int x0 = (int)floorf(px), y0 = (int)floorf(py), z0 = (int)floorf(pz);
        int xlo = max(0, x0 - 3), xhi = min(127, x0 + 4);
        int ylo = max(0, y0 - 3), yhi = min(127, y0 + 4);
        int zlo = max(0, z0 - 3), zhi = min(127, z0 + 4);
        if (xlo > xhi || ylo > yhi || zlo > zhi) continue;
        int pxl = xlo >> 4, pxh = xhi >> 4;      // x-pair index
        int tyl = ylo >> 3, tyh = yhi >> 3;
        int tzl = zlo >> 3, tzh = zhi >> 3;
        for (int tz = tzl; tz <= tzh; ++tz)
            for (int ty = tyl; ty <= tyh; ++ty)
                for (int px2 = pxl; px2 <= pxh; ++px2)
                    flags[((b * 16 + tz) * 16 + ty) * 8 + px2] = 1;
    }
}

// ---------------------------------------------------------------------------
// Per-axis composed 7-tap coefficients (A^3, zero-padded 3-tap average):
// interior [1,3,6,7,6,3,1]/27; boundary rows via cm1/c0/cp1 overrides.
// ---------------------------------------------------------------------------
__device__ __forceinline__ void coef(int g, float& cm1, float& c0, float& cp1)
{
    cm1 = (g == 1 || g == 127) ? 5.f : 6.f;
    c0  = (g == 0 || g == 127) ? 4.f : 7.f;
    cp1 = (g == 0 || g == 126) ? 5.f : 6.f;
}

// ---------------------------------------------------------------------------
// Persistent tile kernel over ALL 32768 pairs: 1024 blocks (4/CU at 34.5 KB
// LDS) grid-stride. Inactive pair -> 4 KB zero store (no LDS churn, blocks
// are persistent; BW work interleaves with active blocks' LDS/VALU work).
// Active pair -> splat into 22x14x14 LDS tile, smooth z/y/x IN PLACE with
// per-column register rolling, divide, store 16x8x8.
// ---------------------------------------------------------------------------
__global__ __launch_bounds__(512, 8)
void tile_persist(const float4* __restrict__ pts,
                  const unsigned char* __restrict__ flags,
                  float* __restrict__ out)
{
    __shared__ float2 raw[14 * 14 * 22];   // 34,496 B

    const int t = threadIdx.x;

    for (int code = blockIdx.x; code < NPAIRS; code += gridDim.x) {
        const int pair = code & 7;
        const int ty   = (code >> 3) & 15;
        const int tz   = (code >> 7) & 15;
        const int b    = code >> 11;
        const int Tx = pair * 16, Ty = ty * 8, Tz = tz * 8;

        float* ob = out + (((size_t)(b * NVOX + Tz) * NVOX + Ty) * NVOX + Tx);

        if (flags[code] == 0) {
            // exact zeros: 256 float4 stores (uniform branch, no barrier used)
            if (t < 256) {
                int x4 = t & 3, y = (t >> 2) & 7, z = t >> 5;
                *(float4*)&ob[((size_t)z * NVOX + y) * NVOX + x4 * 4] =
                    make_float4(0.f, 0.f, 0.f, 0.f);
            }
            continue;
        }

        {   // zero the LDS tile (float4 fill)
            float4* rz = (float4*)raw;
            for (int u = t; u < 2156; u += 512) rz[u] = make_float4(0.f, 0.f, 0.f, 0.f);
        }
        __syncthreads();

        // scatter this batch's points (raw covers [T-3, T+{19,11,11}))
        const float4* pb = pts + b * NPT;
        for (int p = t; p < NPT; p += 512) {
            float4 pt = pb[p];
            float x0f = floorf(pt.x), y0f = floorf(pt.y), z0f = floorf(pt.z);
            int x0 = (int)x0f, y0 = (int)y0f, z0 = (int)z0f;
            int lx0 = x0 - Tx + 3, ly0 = y0 - Ty + 3, lz0 = z0 - Tz + 3;
            if (lx0 + 1 < 0 || lx0 > 21 || ly0 + 1 < 0 || ly0 > 13 ||
                lz0 + 1 < 0 || lz0 > 13) continue;
            float fx = pt.x - x0f, fy = pt.y - y0f, fz = pt.z - z0f;
            float val = pt.w;
            #pragma unroll
            for (int dz = 0; dz < 2; ++dz) {
                int zi = z0 + dz, lz = lz0 + dz;
                if ((unsigned)zi >= 128u || (unsigned)lz >= 14u) continue;
                float wz = dz ? fz : 1.f - fz;
                #pragma unroll
                for (int dy = 0; dy < 2; ++dy) {
                    int yi = y0 + dy, ly = ly0 + dy;
                    if ((unsigned)yi >= 128u || (unsigned)ly >= 14u) continue;
                    float wy = dy ? fy : 1.f - fy;
                    #pragma unroll
                    for (int dx = 0; dx < 2; ++dx) {
                        int xi = x0 + dx, lx = lx0 + dx;
                        if ((unsigned)xi >= 128u || (unsigned)lx >= 22u) continue;
                        float w = (dx ? fx : 1.f - fx) * wy * wz;
                        float2* cell = &raw[(lz * 14 + ly) * 22 + lx];
                        atomicAdd(&cell->x, w * val);
                        atomicAdd(&cell->y, w);
                    }
                }
            }
        }
        __syncthreads();

        // z-pass IN PLACE: column (ly,lx) = t, stride 308. 14 reads -> 8 outputs.
        if (t < 308) {
            float2 w0 = raw[t],           w1 = raw[t + 308],     w2 = raw[t + 2 * 308],
                   w3 = raw[t + 3 * 308], w4 = raw[t + 4 * 308], w5 = raw[t + 5 * 308],
                   w6 = raw[t + 6 * 308];
            #pragma unroll
            for (int z = 0; z < 8; ++z) {
                float cm1, c0, cp1; coef(Tz + z, cm1, c0, cp1);
                float sx = (w0.x + w6.x) + 3.f * (w1.x + w5.x)
                         + cm1 * w2.x + c0 * w3.x + cp1 * w4.x;
                float sy = (w0.y + w6.y) + 3.f * (w1.y + w5.y)
                         + cm1 * w2.y + c0 * w3.y + cp1 * w4.y;
                float2 nxt = raw[t + ((z < 7) ? z + 7 : 7) * 308];  // in-bounds; dummy at z=7
                raw[t + z * 308] = f2(sx * (1.f / 27.f), sy * (1.f / 27.f));
                w0 = w1; w1 = w2; w2 = w3; w3 = w4; w4 = w5; w5 = w6; w6 = nxt;
            }
        }
        __syncthreads();

        // y-pass IN PLACE: column (z,lx), z<8, stride 22. 14 reads -> 8 outputs.
        if (t < 176) {
            int z = t / 22, lx = t - z * 22;
            float2* base = &raw[z * 308 + lx];
            float2 w0 = base[0],      w1 = base[22],     w2 = base[2 * 22],
                   w3 = base[3 * 22], w4 = base[4 * 22], w5 = base[5 * 22],
                   w6 = base[6 * 22];
            #pragma unroll
            for (int y = 0; y < 8; ++y) {
                float cm1, c0, cp1; coef(Ty + y, cm1, c0, cp1);
                float sx = (w0.x + w6.x) + 3.f * (w1.x + w5.x)
                         + cm1 * w2.x + c0 * w3.x + cp1 * w4.x;
                float sy = (w0.y + w6.y) + 3.f * (w1.y + w5.y)
                         + cm1 * w2.y + c0 * w3.y + cp1 * w4.y;
                float2 nxt = base[((y < 7) ? y + 7 : 7) * 22];      // in-bounds; dummy at y=7
                base[y * 22] = f2(sx * (1.f / 27.f), sy * (1.f / 27.f));
                w0 = w1; w1 = w2; w2 = w3; w3 = w4; w4 = w5; w5 = w6; w6 = nxt;
            }
        }
        __syncthreads();

        // x-pass + division: 2 threads per (z,y) row, 8 outputs each
        if (t < 128) {
            int row = t >> 1, half = t & 1;
            int z = row >> 3, y = row & 7;
            const float2* a = &raw[z * 308 + y * 22 + half * 8];
            float2 w0 = a[0], w1 = a[1], w2 = a[2], w3 = a[3],
                   w4 = a[4], w5 = a[5], w6 = a[6];
            float res[8];
            #pragma unroll
            for (int i = 0; i < 8; ++i) {
                int x = half * 8 + i;
                float cm1, c0, cp1; coef(Tx + x, cm1, c0, cp1);
                float sx = (w0.x + w6.x) + 3.f * (w1.x + w5.x)
                         + cm1 * w2.x + c0 * w3.x + cp1 * w4.x;
                float sy = (w0.y + w6.y) + 3.f * (w1.y + w5.y)
                         + cm1 * w2.y + c0 * w3.y + cp1 * w4.y;
                res[i] = (sx * (1.f / 27.f)) / (sy * (1.f / 27.f) + 0.001f);
                float2 nxt = a[(i < 7) ? i + 7 : 13];               // in-bounds; dummy at i=7
                w0 = w1; w1 = w2; w2 = w3; w3 = w4; w4 = w5; w5 = w6; w6 = nxt;
            }
            float* orow = &ob[((size_t)z * NVOX + y) * NVOX + half * 8];
            *(float4*)&orow[0] = make_float4(res[0], res[1], res[2], res[3]);
            *(float4*)&orow[4] = make_float4(res[4], res[5], res[6], res[7]);
        }
        __syncthreads();   // x-pass reads raw; next iteration re-zeroes it
    }
}

// ---------------------------------------------------------------------------
extern "C" void kernel_launch(void* const* d_in, const int* in_sizes, int n_in,
                              void* d_out, int out_size, void* d_ws, size_t ws_size,
                              hipStream_t stream)
{
    const float* q    = (const float*)d_in[0];
    const float* qval = (const float*)d_in[1];
    const float* w1   = (const float*)d_in[2];
    const float* b1   = (const float*)d_in[3];
    const float* w2   = (const float*)d_in[4];
    const float* b2   = (const float*)d_in[5];
    const float* w3   = (const float*)d_in[6];
    const float* b3   = (const float*)d_in[7];
    const float* w4   = (const float*)d_in[8];
    const float* b4   = (const float*)d_in[9];
    const float* w5   = (const float*)d_in[10];
    const float* b5   = (const float*)d_in[11];
    float* out = (float*)d_out;

    // ws layout:
    //   [0,     32768)  pair flags (16 b * 16 tz * 16 ty * 8 px)
    //   [32768,524288)  pts  (1920*16 float4)
    //   [524288,647168) x1g  (1920*16 floats)
    unsigned char* flags = (unsigned char*)d_ws;
    float4* pts = (float4*)((char*)d_ws + 32768);
    float*  x1g = (float*)((char*)d_ws + 524288);

    hipMemsetAsync(d_ws, 0, 32768, stream);

    mlp_stage1<<<240, 256, 0, stream>>>(q, w1, b1, x1g);

    mlp_tail<<<NB, 1024, 0, stream>>>(x1g, qval, w2, b2, w3, b3,
                                      w4, b4, w5, b5, pts, flags);

    tile_persist<<<1024, 512, 0, stream>>>(pts, flags, out);
}

// Round 4
// 232.451 us; speedup vs baseline: 1.9607x; 1.9607x over previous
//
#include <hip/hip_runtime.h>
#include <cstddef>

// Problem constants
#define NB 16
#define NVOX 128
#define NPT 1920
#define NPAIRS 32768   // 16 b * 16 tz * 16 ty * 8 x-pairs

static __device__ __forceinline__ float2 f2(float a, float b) {
    float2 r; r.x = a; r.y = b; return r;
}

// ---------------------------------------------------------------------------
// Zero the whole output at full write BW. grid 4096 x 256, float4 stores.
// Active tiles get overwritten by tile_persist later (~15% extra writes).
// ---------------------------------------------------------------------------
__global__ __launch_bounds__(256)
void zero_out(float4* __restrict__ out)
{
    int idx = blockIdx.x * 2048 + threadIdx.x;
    #pragma unroll
    for (int i = 0; i < 8; ++i)
        out[idx + i * 256] = make_float4(0.f, 0.f, 0.f, 0.f);
}

// ---------------------------------------------------------------------------
// Mega tail: stage1 GEMM + wave-per-channel MLP + point gen + LDS-flag
// compaction, one block per batch (16 x 1024).
//
// stage1: out(240,8) per batch; thread u computes one output via 256-MAC dot
// (float4 w1 reads from L2, q staged in LDS). Written to LDS x1s (flat
// (64,30) view).
//
// MLP: grouped convs never mix channels, so final channel c3 = wave w
// depends only on IN1 channels 4w..4w+3. Each wave carries
// IN1 -> conv2 -> IN2 -> conv3 -> IN3 -> IN4-stats in registers with
// __shfl_xor butterflies. Lane layout: c1_local = lane>>4, p16 = lane&15;
// lane owns row elements {p16, p16+16 (if <30)}.
//
// Compaction: pair flags in LDS; after the final barrier, flagged pairs are
// appended to the global list via atomicAdd (replaces compact_tiles kernel).
// ---------------------------------------------------------------------------
__global__ __launch_bounds__(1024)
void mega_tail(const float* __restrict__ q, const float* __restrict__ w1,
               const float* __restrict__ b1, const float* __restrict__ qval,
               const float* __restrict__ w2, const float* __restrict__ b2,
               const float* __restrict__ w3, const float* __restrict__ b3,
               const float* __restrict__ w4, const float* __restrict__ b4,
               const float* __restrict__ w5, const float* __restrict__ b5,
               float4* __restrict__ pts, int* __restrict__ count,
               int* __restrict__ list)
{
    __shared__ float qs[2048];          //  8 KB staged q[b]
    __shared__ float x1s[1920];         //  7.5 KB stage1 output, flat (64,30)
    __shared__ float h3[16 * 480];      // 30 KB relu'd IN3 output (c3, 480)
    __shared__ float m4s[16], r4s[16];
    __shared__ unsigned char lflags[2048];  // tz16 * ty16 * px8

    const int b = blockIdx.x;
    const int t = threadIdx.x;

    // --- stage q[b] into LDS; zero pair flags ---
    for (int u = t; u < 2048; u += 1024) {
        qs[u] = q[b * 2048 + u];
        lflags[u] = 0;
    }
    __syncthreads();

    // --- stage1: x1[(o,l)] = b1[o] + sum_i w1[o,i] * q[b, i*8+l] ---
    for (int u = t; u < 1920; u += 1024) {
        int o = u >> 3, l = u & 7;
        const float4* wr = (const float4*)(w1 + o * 256);
        float acc = 0.f;
        #pragma unroll 8
        for (int i4 = 0; i4 < 64; ++i4) {
            float4 w = wr[i4];
            int base = i4 * 32 + l;
            acc = fmaf(w.x, qs[base],      acc);
            acc = fmaf(w.y, qs[base + 8],  acc);
            acc = fmaf(w.z, qs[base + 16], acc);
            acc = fmaf(w.w, qs[base + 24], acc);
        }
        x1s[u] = b1[o] + acc;
    }
    __syncthreads();

    // --- wave-per-channel MLP chain ---
    const int w = t >> 6;        // wave id == final channel c3
    const int l = t & 63;
    const int c1l = l >> 4;      // 0..3
    const int p16 = l & 15;
    const int c1  = 4 * w + c1l;
    const bool hasb = (p16 < 14);   // second element p16+16 < 30

    const float* xrow = x1s + c1 * 30;
    float a0 = xrow[p16];
    float a1 = hasb ? xrow[p16 + 16] : 0.f;

    // IN1 over 30 elems: butterfly within the 16-lane channel group
    float s = a0 + a1, s2 = a0 * a0 + a1 * a1;
    #pragma unroll
    for (int m = 1; m <= 8; m <<= 1) {
        s  += __shfl_xor(s,  m);
        s2 += __shfl_xor(s2, m);
    }
    float mean = s * (1.f / 30.f);
    float var  = s2 * (1.f / 30.f) - mean * mean;
    float rstd = rsqrtf(var + 1e-5f);
    a0 = fmaxf((a0 - mean) * rstd, 0.f);
    a1 = fmaxf((a1 - mean) * rstd, 0.f);    // garbage if !hasb; masked below

    // stage2: grouped conv 64->128 (per-lane elementwise)
    const float w20 = w2[c1 * 2 + 0], w21 = w2[c1 * 2 + 1];
    const float b20 = b2[c1 * 2 + 0], b21 = b2[c1 * 2 + 1];
    float y00 = fmaf(a0, w20, b20), y01 = fmaf(a0, w21, b21);
    float y10 = fmaf(a1, w20, b20), y11 = fmaf(a1, w21, b21);

    // IN2 over 120 elems: butterfly within the 32-lane half (c2 group)
    float u1 = y00 + y01 + (hasb ? (y10 + y11) : 0.f);
    float u2 = y00 * y00 + y01 * y01 + (hasb ? (y10 * y10 + y11 * y11) : 0.f);
    #pragma unroll
    for (int m = 1; m <= 16; m <<= 1) {
        u1 += __shfl_xor(u1, m);
        u2 += __shfl_xor(u2, m);
    }
    mean = u1 * (1.f / 120.f);
    var  = u2 * (1.f / 120.f) - mean * mean;
    rstd = rsqrtf(var + 1e-5f);
    y00 = fmaxf((y00 - mean) * rstd, 0.f);
    y01 = fmaxf((y01 - mean) * rstd, 0.f);
    y10 = fmaxf((y10 - mean) * rstd, 0.f);
    y11 = fmaxf((y11 - mean) * rstd, 0.f);

    // stage3: grouped conv 32->64
    const int c2 = c1 >> 1;
    const float w30 = w3[c2 * 2 + 0], w31 = w3[c2 * 2 + 1];
    const float b30 = b3[c2 * 2 + 0], b31 = b3[c2 * 2 + 1];
    float z000 = fmaf(y00, w30, b30), z001 = fmaf(y00, w31, b31);
    float z010 = fmaf(y01, w30, b30), z011 = fmaf(y01, w31, b31);
    float z100 = fmaf(y10, w30, b30), z101 = fmaf(y10, w31, b31);
    float z110 = fmaf(y11, w30, b30), z111 = fmaf(y11, w31, b31);

    // IN3 over 480 elems: full-wave butterfly
    float v1 = z000 + z001 + z010 + z011
             + (hasb ? (z100 + z101 + z110 + z111) : 0.f);
    float v2 = z000 * z000 + z001 * z001 + z010 * z010 + z011 * z011
             + (hasb ? (z100 * z100 + z101 * z101 + z110 * z110 + z111 * z111) : 0.f);
    #pragma unroll
    for (int m = 1; m <= 32; m <<= 1) {
        v1 += __shfl_xor(v1, m);
        v2 += __shfl_xor(v2, m);
    }
    mean = v1 * (1.f / 480.f);
    var  = v2 * (1.f / 480.f) - mean * mean;
    rstd = rsqrtf(var + 1e-5f);

    // normalize+relu, store to h3, accumulate relu'd sums for IN4
    // p(global in 480) = ((c2&1)*2 + j2)*120 + ((c1&1)*2 + j1)*30 + p1
    const int qb0 = (c1l >> 1) * 240;        // (c2&1)*2*120
    const int pb0 = (c1l & 1) * 60;          // (c1&1)*2*30
    float* hw = h3 + w * 480;
    float s4 = 0.f, q4 = 0.f;
    {
        float v;
        v = fmaxf((z000 - mean) * rstd, 0.f); hw[qb0 +       pb0 +      p16] = v; s4 += v; q4 += v * v;
        v = fmaxf((z001 - mean) * rstd, 0.f); hw[qb0 + 120 + pb0 +      p16] = v; s4 += v; q4 += v * v;
        v = fmaxf((z010 - mean) * rstd, 0.f); hw[qb0 +       pb0 + 30 + p16] = v; s4 += v; q4 += v * v;
        v = fmaxf((z011 - mean) * rstd, 0.f); hw[qb0 + 120 + pb0 + 30 + p16] = v; s4 += v; q4 += v * v;
        if (hasb) {
            v = fmaxf((z100 - mean) * rstd, 0.f); hw[qb0 +       pb0 +      p16 + 16] = v; s4 += v; q4 += v * v;
            v = fmaxf((z101 - mean) * rstd, 0.f); hw[qb0 + 120 + pb0 +      p16 + 16] = v; s4 += v; q4 += v * v;
            v = fmaxf((z110 - mean) * rstd, 0.f); hw[qb0 +       pb0 + 30 + p16 + 16] = v; s4 += v; q4 += v * v;
            v = fmaxf((z111 - mean) * rstd, 0.f); hw[qb0 + 120 + pb0 + 30 + p16 + 16] = v; s4 += v; q4 += v * v;
        }
    }
    #pragma unroll
    for (int m = 1; m <= 32; m <<= 1) {
        s4 += __shfl_xor(s4, m);
        q4 += __shfl_xor(q4, m);
    }
    if (l == 0) {
        // stage4 IN stats analytically: x4[c, j*480+p] = h3[c,p]*w4[c*4+j]+b4[c*4+j]
        float sum4 = 0.f, sq4 = 0.f;
        #pragma unroll
        for (int j = 0; j < 4; ++j) {
            float ww = w4[w * 4 + j], bb = b4[w * 4 + j];
            sum4 += ww * s4 + 480.f * bb;
            sq4  += ww * ww * q4 + 2.f * ww * bb * s4 + 480.f * bb * bb;
        }
        float m4 = sum4 * (1.f / 1920.f);
        float var4 = sq4 * (1.f / 1920.f) - m4 * m4;
        m4s[w] = m4; r4s[w] = rsqrtf(var4 + 1e-5f);
    }
    __syncthreads();

    // --- per-point: stage4 apply + stage5 einsum + tanh + emit + mark pairs ---
    for (int p = t; p < NPT; p += 1024) {
        int j = p / 480;
        int pp = p - j * 480;
        float a0e = b5[0], a1e = b5[1], a2e = b5[2];
        #pragma unroll
        for (int c = 0; c < 16; ++c) {
            float xv = h3[c * 480 + pp];
            float x4 = fmaf(xv, w4[c * 4 + j], b4[c * 4 + j]);
            float h  = fmaxf((x4 - m4s[c]) * r4s[c], 0.f);
            a0e = fmaf(w5[c],      h, a0e);
            a1e = fmaf(w5[16 + c], h, a1e);
            a2e = fmaf(w5[32 + c], h, a2e);
        }
        float px = tanhf(a0e) * 64.f + 63.5f;
        float py = tanhf(a1e) * 64.f + 63.5f;
        float pz = tanhf(a2e) * 64.f + 63.5f;
        float val = 1.f / (1.f + expf(-qval[p]));

        float4 pv; pv.x = px; pv.y = py; pv.z = pz; pv.w = val;
        pts[b * NPT + p] = pv;

        int x0 = (int)floorf(px), y0 = (int)floorf(py), z0 = (int)floorf(pz);
        int xlo = max(0, x0 - 3), xhi = min(127, x0 + 4);
        int ylo = max(0, y0 - 3), yhi = min(127, y0 + 4);
        int zlo = max(0, z0 - 3), zhi = min(127, z0 + 4);
        if (xlo > xhi || ylo > yhi || zlo > zhi) continue;
        int pxl = xlo >> 4, pxh = xhi >> 4;      // x-pair index
        int tyl = ylo >> 3, tyh = yhi >> 3;
        int tzl = zlo >> 3, tzh = zhi >> 3;
        for (int tz = tzl; tz <= tzh; ++tz)
            for (int ty = tyl; ty <= tyh; ++ty)
                for (int px2 = pxl; px2 <= pxh; ++px2)
                    lflags[(tz * 16 + ty) * 8 + px2] = 1;
    }
    __syncthreads();

    // --- compact this batch's active pairs into the global list ---
    for (int u = t; u < 2048; u += 1024) {
        if (lflags[u]) {
            int pos = atomicAdd(count, 1);
            list[pos] = b * 2048 + u;
        }
    }
}

// ---------------------------------------------------------------------------
// Per-axis composed 7-tap coefficients (A^3, zero-padded 3-tap average):
// interior [1,3,6,7,6,3,1]/27; boundary rows via cm1/c0/cp1 overrides.
// ---------------------------------------------------------------------------
__device__ __forceinline__ void coef(int g, float& cm1, float& c0, float& cp1)
{
    cm1 = (g == 1 || g == 127) ? 5.f : 6.f;
    c0  = (g == 0 || g == 127) ? 4.f : 7.f;
    cp1 = (g == 0 || g == 126) ? 5.f : 6.f;
}

// ---------------------------------------------------------------------------
// Persistent active-tile kernel (round-2 proven): 1024 blocks grid-stride
// over the compacted list. Splat into 22x14x14 LDS tile, smooth z/y/x
// IN PLACE with per-column register rolling, divide, store 16x8x8.
// In-place safety: output index g only overwrites input g, which no later
// output of the same column reads; columns are thread-private.
// ---------------------------------------------------------------------------
__global__ __launch_bounds__(512, 8)
void tile_persist(const float4* __restrict__ pts, const int* __restrict__ count,
                  const int* __restrict__ list, float* __restrict__ out)
{
    __shared__ float2 raw[14 * 14 * 22];   // 34,496 B

    const int cnt = *count;
    const int t = threadIdx.x;

    for (int idx = blockIdx.x; idx < cnt; idx += gridDim.x) {
        const int code = list[idx];
        const int pair = code & 7;
        const int ty   = (code >> 3) & 15;
        const int tz   = (code >> 7) & 15;
        const int b    = code >> 11;
        const int Tx = pair * 16, Ty = ty * 8, Tz = tz * 8;

        float* ob = out + (((size_t)(b * NVOX + Tz) * NVOX + Ty) * NVOX + Tx);

        {   // zero the LDS tile (float4 fill)
            float4* rz = (float4*)raw;
            for (int u = t; u < 2156; u += 512) rz[u] = make_float4(0.f, 0.f, 0.f, 0.f);
        }
        __syncthreads();

        // scatter this batch's points (raw covers [T-3, T+{19,11,11}))
        const float4* pb = pts + b * NPT;
        for (int p = t; p < NPT; p += 512) {
            float4 pt = pb[p];
            float x0f = floorf(pt.x), y0f = floorf(pt.y), z0f = floorf(pt.z);
            int x0 = (int)x0f, y0 = (int)y0f, z0 = (int)z0f;
            int lx0 = x0 - Tx + 3, ly0 = y0 - Ty + 3, lz0 = z0 - Tz + 3;
            if (lx0 + 1 < 0 || lx0 > 21 || ly0 + 1 < 0 || ly0 > 13 ||
                lz0 + 1 < 0 || lz0 > 13) continue;
            float fx = pt.x - x0f, fy = pt.y - y0f, fz = pt.z - z0f;
            float val = pt.w;
            #pragma unroll
            for (int dz = 0; dz < 2; ++dz) {
                int zi = z0 + dz, lz = lz0 + dz;
                if ((unsigned)zi >= 128u || (unsigned)lz >= 14u) continue;
                float wz = dz ? fz : 1.f - fz;
                #pragma unroll
                for (int dy = 0; dy < 2; ++dy) {
                    int yi = y0 + dy, ly = ly0 + dy;
                    if ((unsigned)yi >= 128u || (unsigned)ly >= 14u) continue;
                    float wy = dy ? fy : 1.f - fy;
                    #pragma unroll
                    for (int dx = 0; dx < 2; ++dx) {
                        int xi = x0 + dx, lx = lx0 + dx;
                        if ((unsigned)xi >= 128u || (unsigned)lx >= 22u) continue;
                        float w = (dx ? fx : 1.f - fx) * wy * wz;
                        float2* cell = &raw[(lz * 14 + ly) * 22 + lx];
                        atomicAdd(&cell->x, w * val);
                        atomicAdd(&cell->y, w);
                    }
                }
            }
        }
        __syncthreads();

        // z-pass IN PLACE: column (ly,lx) = t, stride 308. 14 reads -> 8 outputs.
        if (t < 308) {
            float2 w0 = raw[t],           w1 = raw[t + 308],     w2 = raw[t + 2 * 308],
                   w3 = raw[t + 3 * 308], w4 = raw[t + 4 * 308], w5 = raw[t + 5 * 308],
                   w6 = raw[t + 6 * 308];
            #pragma unroll
            for (int z = 0; z < 8; ++z) {
                float cm1, c0, cp1; coef(Tz + z, cm1, c0, cp1);
                float sx = (w0.x + w6.x) + 3.f * (w1.x + w5.x)
                         + cm1 * w2.x + c0 * w3.x + cp1 * w4.x;
                float sy = (w0.y + w6.y) + 3.f * (w1.y + w5.y)
                         + cm1 * w2.y + c0 * w3.y + cp1 * w4.y;
                float2 nxt = raw[t + ((z < 7) ? z + 7 : 7) * 308];  // in-bounds; dummy at z=7
                raw[t + z * 308] = f2(sx * (1.f / 27.f), sy * (1.f / 27.f));
                w0 = w1; w1 = w2; w2 = w3; w3 = w4; w4 = w5; w5 = w6; w6 = nxt;
            }
        }
        __syncthreads();

        // y-pass IN PLACE: column (z,lx), z<8, stride 22. 14 reads -> 8 outputs.
        if (t < 176) {
            int z = t / 22, lx = t - z * 22;
            float2* base = &raw[z * 308 + lx];
            float2 w0 = base[0],      w1 = base[22],     w2 = base[2 * 22],
                   w3 = base[3 * 22], w4 = base[4 * 22], w5 = base[5 * 22],
                   w6 = base[6 * 22];
            #pragma unroll
            for (int y = 0; y < 8; ++y) {
                float cm1, c0, cp1; coef(Ty + y, cm1, c0, cp1);
                float sx = (w0.x + w6.x) + 3.f * (w1.x + w5.x)
                         + cm1 * w2.x + c0 * w3.x + cp1 * w4.x;
                float sy = (w0.y + w6.y) + 3.f * (w1.y + w5.y)
                         + cm1 * w2.y + c0 * w3.y + cp1 * w4.y;
                float2 nxt = base[((y < 7) ? y + 7 : 7) * 22];      // in-bounds; dummy at y=7
                base[y * 22] = f2(sx * (1.f / 27.f), sy * (1.f / 27.f));
                w0 = w1; w1 = w2; w2 = w3; w3 = w4; w4 = w5; w5 = w6; w6 = nxt;
            }
        }
        __syncthreads();

        // x-pass + division: 2 threads per (z,y) row, 8 outputs each
        if (t < 128) {
            int row = t >> 1, half = t & 1;
            int z = row >> 3, y = row & 7;
            const float2* a = &raw[z * 308 + y * 22 + half * 8];
            float2 w0 = a[0], w1 = a[1], w2 = a[2], w3 = a[3],
                   w4 = a[4], w5 = a[5], w6 = a[6];
            float res[8];
            #pragma unroll
            for (int i = 0; i < 8; ++i) {
                int x = half * 8 + i;
                float cm1, c0, cp1; coef(Tx + x, cm1, c0, cp1);
                float sx = (w0.x + w6.x) + 3.f * (w1.x + w5.x)
                         + cm1 * w2.x + c0 * w3.x + cp1 * w4.x;
                float sy = (w0.y + w6.y) + 3.f * (w1.y + w5.y)
                         + cm1 * w2.y + c0 * w3.y + cp1 * w4.y;
                res[i] = (sx * (1.f / 27.f)) / (sy * (1.f / 27.f) + 0.001f);
                float2 nxt = a[(i < 7) ? i + 7 : 13];               // in-bounds; dummy at i=7
                w0 = w1; w1 = w2; w2 = w3; w3 = w4; w4 = w5; w5 = w6; w6 = nxt;
            }
            float* orow = &ob[((size_t)z * NVOX + y) * NVOX + half * 8];
            *(float4*)&orow[0] = make_float4(res[0], res[1], res[2], res[3]);
            *(float4*)&orow[4] = make_float4(res[4], res[5], res[6], res[7]);
        }
        __syncthreads();   // x-pass reads raw; next iteration re-zeroes it
    }
}

// ---------------------------------------------------------------------------
extern "C" void kernel_launch(void* const* d_in, const int* in_sizes, int n_in,
                              void* d_out, int out_size, void* d_ws, size_t ws_size,
                              hipStream_t stream)
{
    const float* q    = (const float*)d_in[0];
    const float* qval = (const float*)d_in[1];
    const float* w1   = (const float*)d_in[2];
    const float* b1   = (const float*)d_in[3];
    const float* w2   = (const float*)d_in[4];
    const float* b2   = (const float*)d_in[5];
    const float* w3   = (const float*)d_in[6];
    const float* b3   = (const float*)d_in[7];
    const float* w4   = (const float*)d_in[8];
    const float* b4   = (const float*)d_in[9];
    const float* w5   = (const float*)d_in[10];
    const float* b5   = (const float*)d_in[11];
    float* out = (float*)d_out;

    // ws layout:
    //   [0,         4)  count
    //   [16,   131088)  list (32768 ints)
    //   [131088, 622608) pts (1920*16 float4)
    int*    count = (int*)d_ws;
    int*    list  = (int*)((char*)d_ws + 16);
    float4* pts   = (float4*)((char*)d_ws + 131088);

    hipMemsetAsync(count, 0, 4, stream);

    zero_out<<<4096, 256, 0, stream>>>((float4*)out);

    mega_tail<<<NB, 1024, 0, stream>>>(q, w1, b1, qval, w2, b2, w3, b3,
                                       w4, b4, w5, b5, pts, count, list);

    tile_persist<<<1024, 512, 0, stream>>>(pts, count, list, out);
}